// Round 2
// baseline (152.054 us; speedup 1.0000x reference)
//
#include <hip/hip_runtime.h>
#include <math.h>

// Problem constants (from reference setup_inputs): B=4, N=M=8192, fp32, SCALE=1.0
#define BATCH   4
#define NPTS    8192
#define TCHUNKS 8
#define CHUNK   (NPTS / TCHUNKS)   // 1024 targets staged in LDS per block
#define THREADS 256
#define QPT     4                  // query points per thread (registers)
#define QPB     (THREADS * QPT)    // 1024 queries per block
#define QTILES  (NPTS / QPB)       // 8

static constexpr float SCALE = 1.0f;

// Partial-min layout in d_ws: pm[((dir*BATCH + b)*NPTS + q)*TCHUNKS + chunk]
// -> 2*4*8192*8 floats = 2 MB. Written exactly once per slot (poison-safe).
#define PM_ELEMS (2 * BATCH * NPTS * TCHUNKS)

__global__ __launch_bounds__(THREADS)
void chamfer_min_kernel(const float* __restrict__ p1,
                        const float* __restrict__ p2,
                        float* __restrict__ pm)
{
    // 12 KB LDS: CHUNK targets * 3 floats
    __shared__ float4 lds4[CHUNK * 3 / 4];

    const int bid = blockIdx.x;                 // 512 blocks
    const int c   = bid & (TCHUNKS - 1);        // target chunk
    const int qt  = (bid >> 3) & (QTILES - 1);  // query tile
    const int b   = (bid >> 6) & (BATCH - 1);   // batch
    const int dir = bid >> 8;                   // 0: q=p1,t=p2  1: q=p2,t=p1

    const float* qptr = (dir == 0 ? p1 : p2) + (size_t)b * NPTS * 3;
    const float* tptr = (dir == 0 ? p2 : p1) + (size_t)b * NPTS * 3;

    // Stage target chunk -> LDS (coalesced float4), applying SCALE.
    const float4* tsrc = reinterpret_cast<const float4*>(tptr + (size_t)c * CHUNK * 3);
    #pragma unroll
    for (int i = threadIdx.x; i < CHUNK * 3 / 4; i += THREADS) {
        float4 v = tsrc[i];
        v.x *= SCALE; v.y *= SCALE; v.z *= SCALE; v.w *= SCALE;
        lds4[i] = v;
    }

    // Four query points per thread (registers): q0, q0+256, q0+512, q0+768.
    const int t  = threadIdx.x;
    const int q0 = qt * QPB + t;
    float qx[QPT], qy[QPT], qz[QPT], qmin[QPT];
    #pragma unroll
    for (int k = 0; k < QPT; ++k) {
        const int q = q0 + k * THREADS;
        qx[k] = qptr[q * 3 + 0] * SCALE;
        qy[k] = qptr[q * 3 + 1] * SCALE;
        qz[k] = qptr[q * 3 + 2] * SCALE;
        qmin[k] = 3.0e38f;
    }

    __syncthreads();

    // Main loop: 8 targets per iteration, uniform LDS reads (broadcast),
    // 32 independent distance chains per thread for ILP.
    for (int j = 0; j < CHUNK; j += 8) {
        alignas(16) float tf[24];
        float4* tf4 = reinterpret_cast<float4*>(tf);
        const int base = (j >> 3) * 6;
        #pragma unroll
        for (int k = 0; k < 6; ++k) tf4[k] = lds4[base + k];

        #pragma unroll
        for (int k = 0; k < QPT; ++k) {
            float d[8];
            #pragma unroll
            for (int i = 0; i < 8; ++i) {
                const float dx = qx[k] - tf[3 * i + 0];
                const float dy = qy[k] - tf[3 * i + 1];
                const float dz = qz[k] - tf[3 * i + 2];
                d[i] = dx * dx + dy * dy + dz * dz;
            }
            // Pairwise mins -> v_min3 opportunities (acc, d[i], d[i+1]).
            #pragma unroll
            for (int i = 0; i < 8; i += 2)
                qmin[k] = fminf(qmin[k], fminf(d[i], d[i + 1]));
        }
    }

    #pragma unroll
    for (int k = 0; k < QPT; ++k) {
        const int q = q0 + k * THREADS;
        pm[((size_t)(dir * BATCH + b) * NPTS + q) * TCHUNKS + c] = qmin[k];
    }
}

// Kernel 2: per-query min over TCHUNKS partials, then per-block sum.
// 65536 queries total (2 dirs * 4 b * 8192), 512 thr/block -> 128 blocks.
// Blocks 0..63 are dir0 entries, 64..127 dir1 (512*64 = 32768 = BATCH*NPTS).
__global__ __launch_bounds__(512)
void chamfer_reduce_kernel(const float* __restrict__ pm,
                           float* __restrict__ bsum)
{
    const int idx = blockIdx.x * 512 + threadIdx.x;  // 0..65535
    const float4* p4 = reinterpret_cast<const float4*>(pm + (size_t)idx * TCHUNKS);
    const float4 u = p4[0];
    const float4 v = p4[1];
    float m = fminf(fminf(fminf(u.x, u.y), fminf(u.z, u.w)),
                    fminf(fminf(v.x, v.y), fminf(v.z, v.w)));

    // Sum across the block (8 waves of 64).
    #pragma unroll
    for (int o = 32; o > 0; o >>= 1) m += __shfl_down(m, o, 64);

    __shared__ float red[8];
    const int wave = threadIdx.x >> 6;
    const int lane = threadIdx.x & 63;
    if (lane == 0) red[wave] = m;
    __syncthreads();
    if (threadIdx.x == 0) {
        float s = 0.0f;
        #pragma unroll
        for (int w = 0; w < 8; ++w) s += red[w];
        bsum[blockIdx.x] = s;
    }
}

// Kernel 3: fold 128 block sums -> scalar. One wave.
__global__ __launch_bounds__(64)
void chamfer_final_kernel(const float* __restrict__ bsum,
                          float* __restrict__ out)
{
    const int t = threadIdx.x;          // 0..63
    float s0 = bsum[t];                 // dir0 block sums
    float s1 = bsum[64 + t];            // dir1 block sums
    #pragma unroll
    for (int o = 32; o > 0; o >>= 1) {
        s0 += __shfl_down(s0, o, 64);
        s1 += __shfl_down(s1, o, 64);
    }
    if (t == 0) {
        out[0] = s0 / (float)(BATCH * NPTS) + s1 / (float)(BATCH * NPTS);
    }
}

extern "C" void kernel_launch(void* const* d_in, const int* in_sizes, int n_in,
                              void* d_out, int out_size, void* d_ws, size_t ws_size,
                              hipStream_t stream) {
    const float* p1 = (const float*)d_in[0];
    const float* p2 = (const float*)d_in[1];
    float* out = (float*)d_out;

    float* pm   = (float*)d_ws;           // 2 MB partial mins
    float* bsum = pm + PM_ELEMS;          // 128 floats

    chamfer_min_kernel<<<2 * BATCH * QTILES * TCHUNKS, THREADS, 0, stream>>>(p1, p2, pm);
    chamfer_reduce_kernel<<<128, 512, 0, stream>>>(pm, bsum);
    chamfer_final_kernel<<<1, 64, 0, stream>>>(bsum, out);
}

// Round 3
// 105.115 us; speedup vs baseline: 1.4465x; 1.4465x over previous
//
#include <hip/hip_runtime.h>
#include <math.h>

// Problem constants (from reference setup_inputs): B=4, N=M=8192, fp32, SCALE=1.0
#define BATCH   4
#define NPTS    8192
#define THREADS 256
#define QPT     4                  // query points per thread (registers)
#define QPB     (THREADS * QPT)    // 1024 queries per block
#define QTILES  (NPTS / QPB)       // 8

static constexpr float SCALE = 1.0f;

// d_ws layout: pm[((dir*BATCH + b)*NPTS + q)*TCH + chunk]  (float)
// then bsum[128]. Every pm slot written exactly once (poison-safe).

// Kernel 1: per (dir, batch, query-tile, target-chunk) block.
// LDS holds CHUNK targets as float4(-2x, -2y, -2z, ||t||^2).
// Per distance: 3 FMA + amortized min3. ||q||^2 added in epilogue
// (constant per query -> commutes with min over targets).
template<int TCH>
__global__ __launch_bounds__(THREADS, 8)
void chamfer_min_kernel(const float* __restrict__ p1,
                        const float* __restrict__ p2,
                        float* __restrict__ pm)
{
    constexpr int CHUNK = NPTS / TCH;      // targets staged per block
    __shared__ float4 lds4[CHUNK];         // CHUNK*16 B (4 KB at TCH=32)

    const int bid = blockIdx.x;
    const int c   = bid % TCH;                    // target chunk
    const int qt  = (bid / TCH) % QTILES;         // query tile
    const int b   = (bid / (TCH * QTILES)) % BATCH;
    const int dir = bid / (TCH * QTILES * BATCH); // 0: q=p1,t=p2  1: q=p2,t=p1

    const float* qptr = (dir == 0 ? p1 : p2) + (size_t)b * NPTS * 3;
    const float* tptr = (dir == 0 ? p2 : p1) + (size_t)b * NPTS * 3;

    // Stage targets -> LDS as (-2x, -2y, -2z, bb).
    const float* tsrc = tptr + (size_t)c * CHUNK * 3;
    for (int i = threadIdx.x; i < CHUNK; i += THREADS) {
        const float x = tsrc[3 * i + 0] * SCALE;
        const float y = tsrc[3 * i + 1] * SCALE;
        const float z = tsrc[3 * i + 2] * SCALE;
        const float bb = fmaf(z, z, fmaf(y, y, x * x));
        lds4[i] = make_float4(-2.0f * x, -2.0f * y, -2.0f * z, bb);
    }

    // Four query points per thread (registers).
    const int t  = threadIdx.x;
    const int q0 = qt * QPB + t;
    float qx[QPT], qy[QPT], qz[QPT], qmin[QPT];
    #pragma unroll
    for (int k = 0; k < QPT; ++k) {
        const int q = q0 + k * THREADS;
        qx[k] = qptr[q * 3 + 0] * SCALE;
        qy[k] = qptr[q * 3 + 1] * SCALE;
        qz[k] = qptr[q * 3 + 2] * SCALE;
        qmin[k] = 3.0e38f;
    }

    __syncthreads();

    // Main loop: 8 targets/iter, uniform (broadcast) LDS reads,
    // 2-target groups keep live temps low (fits 64-VGPR cap).
    for (int j = 0; j < CHUNK; j += 8) {
        #pragma unroll
        for (int i = 0; i < 8; i += 2) {
            const float4 t0 = lds4[j + i];
            const float4 t1 = lds4[j + i + 1];
            #pragma unroll
            for (int k = 0; k < QPT; ++k) {
                float s0 = fmaf(qx[k], t0.x, t0.w);
                s0 = fmaf(qy[k], t0.y, s0);
                s0 = fmaf(qz[k], t0.z, s0);
                float s1 = fmaf(qx[k], t1.x, t1.w);
                s1 = fmaf(qy[k], t1.y, s1);
                s1 = fmaf(qz[k], t1.z, s1);
                qmin[k] = fminf(qmin[k], fminf(s0, s1));  // -> v_min3
            }
        }
    }

    // Epilogue: add ||q||^2 (monotone shift, safe before the chunk-min).
    #pragma unroll
    for (int k = 0; k < QPT; ++k) {
        const float aa = fmaf(qz[k], qz[k], fmaf(qy[k], qy[k], qx[k] * qx[k]));
        const int q = q0 + k * THREADS;
        pm[((size_t)(dir * BATCH + b) * NPTS + q) * TCH + c] = qmin[k] + aa;
    }
}

// Kernel 2: per-query min over TCH partials, clamp to 0, per-block sum.
// 65536 queries / 512 thr -> 128 blocks (0..63 dir0, 64..127 dir1).
template<int TCH>
__global__ __launch_bounds__(512)
void chamfer_reduce_kernel(const float* __restrict__ pm,
                           float* __restrict__ bsum)
{
    const int idx = blockIdx.x * 512 + threadIdx.x;  // 0..65535
    const float4* p4 = reinterpret_cast<const float4*>(pm + (size_t)idx * TCH);
    float m = 3.0e38f;
    #pragma unroll
    for (int i = 0; i < TCH / 4; ++i) {
        const float4 u = p4[i];
        m = fminf(m, fminf(fminf(u.x, u.y), fminf(u.z, u.w)));
    }
    m = fmaxf(m, 0.0f);   // matches reference's max(d, 0) before min

    #pragma unroll
    for (int o = 32; o > 0; o >>= 1) m += __shfl_down(m, o, 64);

    __shared__ float red[8];
    const int wave = threadIdx.x >> 6;
    const int lane = threadIdx.x & 63;
    if (lane == 0) red[wave] = m;
    __syncthreads();
    if (threadIdx.x == 0) {
        float s = 0.0f;
        #pragma unroll
        for (int w = 0; w < 8; ++w) s += red[w];
        bsum[blockIdx.x] = s;
    }
}

// Kernel 3: fold 128 block sums -> scalar. One wave.
__global__ __launch_bounds__(64)
void chamfer_final_kernel(const float* __restrict__ bsum,
                          float* __restrict__ out)
{
    const int t = threadIdx.x;          // 0..63
    float s0 = bsum[t];                 // dir0 block sums
    float s1 = bsum[64 + t];            // dir1 block sums
    #pragma unroll
    for (int o = 32; o > 0; o >>= 1) {
        s0 += __shfl_down(s0, o, 64);
        s1 += __shfl_down(s1, o, 64);
    }
    if (t == 0) {
        out[0] = s0 / (float)(BATCH * NPTS) + s1 / (float)(BATCH * NPTS);
    }
}

template<int TCH>
static void launch_all(const float* p1, const float* p2, float* out,
                       void* d_ws, hipStream_t stream)
{
    float* pm   = (float*)d_ws;
    float* bsum = pm + (size_t)2 * BATCH * NPTS * TCH;

    chamfer_min_kernel<TCH><<<2 * BATCH * QTILES * TCH, THREADS, 0, stream>>>(p1, p2, pm);
    chamfer_reduce_kernel<TCH><<<128, 512, 0, stream>>>(pm, bsum);
    chamfer_final_kernel<<<1, 64, 0, stream>>>(bsum, out);
}

extern "C" void kernel_launch(void* const* d_in, const int* in_sizes, int n_in,
                              void* d_out, int out_size, void* d_ws, size_t ws_size,
                              hipStream_t stream) {
    const float* p1 = (const float*)d_in[0];
    const float* p2 = (const float*)d_in[1];
    float* out = (float*)d_out;

    // ws_size is constant across calls -> this branch is graph-capture safe.
    const size_t need32 = (size_t)2 * BATCH * NPTS * 32 * sizeof(float) + 512;
    if (ws_size >= need32) {
        launch_all<32>(p1, p2, out, d_ws, stream);   // 2048 blocks, 32 waves/CU
    } else {
        launch_all<8>(p1, p2, out, d_ws, stream);    // fallback, 512 blocks
    }
}